// Round 11
// baseline (205.837 us; speedup 1.0000x reference)
//
#include <hip/hip_runtime.h>

#define B_    8
#define N_    1024
#define DIM_  768
#define H_    12
#define DH_   64
#define CTX_  992
#define BH_   (B_ * H_)
#define EPS_  1e-5f
#define WSZ_  (DIM_ * DIM_)
#define PS_   72    // attn Ps row stride (ush)
#define VS_   136   // gemm_qkv VT overlay row stride (ush): 128 cols + 8 pad

typedef unsigned short ush;
typedef __attribute__((ext_vector_type(8))) short bf8_t;   // 8 bf16 (A/B frag)
typedef __attribute__((ext_vector_type(4))) float f4_t;    // 4 fp32 (C/D frag)

__device__ __forceinline__ float b2f(ush u) {
    return __uint_as_float(((unsigned)u) << 16);
}
__device__ __forceinline__ ush f2b(float f) {   // round-to-nearest-even
    unsigned u = __float_as_uint(f);
    u += 0x7fffu + ((u >> 16) & 1u);
    return (ush)(u >> 16);
}
__device__ __forceinline__ void gload_lds16(const void* g, void* l) {
    __builtin_amdgcn_global_load_lds(
        (const __attribute__((address_space(1))) void*)g,
        (__attribute__((address_space(3))) void*)l, 16, 0, 0);
}

// ---------------------------------------------------------------------------
// Merged cast kernel: blocks [0, 6144) cast X fp32->bf16; blocks [6144, 6720)
// transpose+cast the four 768x768 weights (bf16 Wt[n][k] = W[k][n]).
// ---------------------------------------------------------------------------
__global__ __launch_bounds__(256) void cast_all(
    const float* __restrict__ X, ush* __restrict__ Xb,
    const float* __restrict__ W0, const float* __restrict__ W1,
    const float* __restrict__ W2, const float* __restrict__ W3,
    ush* __restrict__ T0, ush* __restrict__ T1,
    ush* __restrict__ T2, ush* __restrict__ T3)
{
    __shared__ ush T[64][65];
    const int bid = blockIdx.x;
    const int tid = threadIdx.x;

    if (bid < 6144) {
        const int i4 = bid * 256 + tid;      // float4 index
        float4 v = *(const float4*)&X[(size_t)i4 * 4];
        ushort4 o;
        o.x = f2b(v.x); o.y = f2b(v.y); o.z = f2b(v.z); o.w = f2b(v.w);
        *(ushort4*)&Xb[(size_t)i4 * 4] = o;
        return;
    }
    const int t = bid - 6144;                // 0..575
    const int z = t / 144, rem = t % 144;
    const int i0 = (rem / 12) * 64;          // k-rows
    const int j0 = (rem % 12) * 64;          // n-cols
    const float* W = (z == 0) ? W0 : (z == 1) ? W1 : (z == 2) ? W2 : W3;
    ush* Wt        = (z == 0) ? T0 : (z == 1) ? T1 : (z == 2) ? T2 : T3;

    const int r4 = tid >> 4, c = (tid & 15) << 2;
    #pragma unroll
    for (int g = 0; g < 4; ++g) {
        const int r = r4 + g * 16;
        float4 v = *(const float4*)&W[(size_t)(i0 + r) * DIM_ + j0 + c];
        T[r][c + 0] = f2b(v.x); T[r][c + 1] = f2b(v.y);
        T[r][c + 2] = f2b(v.z); T[r][c + 3] = f2b(v.w);
    }
    __syncthreads();
    const int nl = tid >> 2, k0l = (tid & 3) << 4;
    #pragma unroll
    for (int g = 0; g < 4; ++g) {
        ushort4 o;
        o.x = T[k0l + 4 * g + 0][nl]; o.y = T[k0l + 4 * g + 1][nl];
        o.z = T[k0l + 4 * g + 2][nl]; o.w = T[k0l + 4 * g + 3][nl];
        *(ushort4*)&Wt[(size_t)(j0 + nl) * DIM_ + i0 + k0l + 4 * g] = o;
    }
}

// ---------------------------------------------------------------------------
// Fused MFMA GEMM + RoPE (+scale for Q; +LN for KV) + V-transpose.
// Tile 128x128, BK=32, XOR-swizzled LDS. z=0: Q16 = rope(acc)*0.125*log2e
// (attn uses exp2). z=1: K16 = rope(acc); LN'd V transposed block-locally
// through an LDS overlay [128 d-rows][VS_] (slot-permuted to match attn's
// packed-P order: within each 64-key tile, slot s holds key (s&3)*16+(s>>2))
// then copied out coalesced -> Vt[bh][d][n].
// ---------------------------------------------------------------------------
__global__ __launch_bounds__(256, 3) void gemm_qkv_mfma(
    const ush* __restrict__ Xb, const ush* __restrict__ Wt0,
    const ush* __restrict__ Wt1, ush* __restrict__ Q16, ush* __restrict__ K16,
    ush* __restrict__ Vt, const float* __restrict__ ln_g,
    const float* __restrict__ ln_b)
{
    const int z   = blockIdx.z;
    const ush* Bt = z ? Wt1 : Wt0;
    const int m0 = blockIdx.y * 128, c0 = blockIdx.x * 128;
    const int tid = threadIdx.x;
    const int w = tid >> 6, lane = tid & 63, l15 = lane & 15, quad = lane >> 4;
    const int wm = w >> 1, wn = w & 1;

    // SMEM union: staging As=SMEM[0,4096), Bs=SMEM[4096,8192) during k-loop;
    // VT overlay [128][VS_] (17408 ush = 34.8 KB) after the loop (z=1 only).
    __shared__ __align__(16) ush SMEM[128 * VS_];
    ush* As = SMEM;
    ush* Bs = SMEM + 4096;

    const int slot0 = w * 2 * 64 + lane;
    const int srow0 = slot0 >> 2, scc0 = (slot0 & 3) ^ (srow0 & 3);
    const int slot1 = slot0 + 64;
    const int srow1 = slot1 >> 2, scc1 = (slot1 & 3) ^ (srow1 & 3);

    f4_t acc[4][4];
    #pragma unroll
    for (int i = 0; i < 4; ++i)
        #pragma unroll
        for (int j = 0; j < 4; ++j)
            #pragma unroll
            for (int r = 0; r < 4; ++r) acc[i][j][r] = 0.f;

    for (int k0 = 0; k0 < DIM_; k0 += 32) {
        __syncthreads();
        gload_lds16((const char*)Xb + (size_t)(m0 + srow0) * (DIM_ * 2) + k0 * 2 + scc0 * 16,
                    (char*)As + slot0 * 16);
        gload_lds16((const char*)Bt + (size_t)(c0 + srow0) * (DIM_ * 2) + k0 * 2 + scc0 * 16,
                    (char*)Bs + slot0 * 16);
        gload_lds16((const char*)Xb + (size_t)(m0 + srow1) * (DIM_ * 2) + k0 * 2 + scc1 * 16,
                    (char*)As + slot1 * 16);
        gload_lds16((const char*)Bt + (size_t)(c0 + srow1) * (DIM_ * 2) + k0 * 2 + scc1 * 16,
                    (char*)Bs + slot1 * 16);
        __syncthreads();

        const int sq = (quad ^ (l15 & 3)) * 8;
        bf8_t af[4];
        #pragma unroll
        for (int mi = 0; mi < 4; ++mi)
            af[mi] = *(const bf8_t*)&As[(wm * 64 + mi * 16 + l15) * 32 + sq];
        #pragma unroll
        for (int ni = 0; ni < 4; ++ni) {
            bf8_t bfr = *(const bf8_t*)&Bs[(wn * 64 + ni * 16 + l15) * 32 + sq];
            #pragma unroll
            for (int mi = 0; mi < 4; ++mi)
                acc[mi][ni] = __builtin_amdgcn_mfma_f32_16x16x32_bf16(
                    af[mi], bfr, acc[mi][ni], 0, 0, 0);
        }
    }

    // ---- fused RoPE epilogue ----
    const float inv0 = __expf(-(float)l15 * (9.210340371976184f / 32.0f));
    const float inv1 = inv0 * 0.01f;    // 10000^(-16/32)
    const int h  = (c0 >> 6) + wn;
    const int b  = (m0 + wm * 64) >> 10;
    const int nb = (m0 + wm * 64) & 1023;

    #pragma unroll
    for (int mi = 0; mi < 4; ++mi) {
        #pragma unroll
        for (int r = 0; r < 4; ++r) {
            const int n = nb + mi * 16 + quad * 4 + r;
            float sn0, cs0, sn1, cs1;
            __sincosf((float)n * inv0, &sn0, &cs0);
            __sincosf((float)n * inv1, &sn1, &cs1);
            {
                float a = acc[mi][0][r], p = acc[mi][2][r];
                acc[mi][0][r] = a * cs0 - p * sn0;
                acc[mi][2][r] = p * cs0 + a * sn0;
            }
            {
                float a = acc[mi][1][r], p = acc[mi][3][r];
                acc[mi][1][r] = a * cs1 - p * sn1;
                acc[mi][3][r] = p * cs1 + a * sn1;
            }
        }
    }

    if (z == 0) {
        // Q path: scale by DH^-0.5 * log2(e) so attn can use exp2 directly
        #pragma unroll
        for (int mi = 0; mi < 4; ++mi)
            #pragma unroll
            for (int ni = 0; ni < 4; ++ni)
                #pragma unroll
                for (int r = 0; r < 4; ++r) {
                    const int n = nb + mi * 16 + quad * 4 + r;
                    const int d = ni * 16 + l15;
                    Q16[(((size_t)b * H_ + h) * N_ + n) * DH_ + d] =
                        f2b(acc[mi][ni][r] * 0.1803368801111731f);
                }
    } else {
        float g4[4], b4[4];
        #pragma unroll
        for (int ni = 0; ni < 4; ++ni) {
            g4[ni] = ln_g[ni * 16 + l15];
            b4[ni] = ln_b[ni * 16 + l15];
        }
        __syncthreads();   // all waves done with As/Bs -> VT overlay is safe
        #pragma unroll
        for (int mi = 0; mi < 4; ++mi)
            #pragma unroll
            for (int r = 0; r < 4; ++r) {
                const int n = nb + mi * 16 + quad * 4 + r;
                const size_t rowoff = (((size_t)b * H_ + h) * N_ + n) * DH_;
                float s = (acc[mi][0][r] + acc[mi][1][r]) +
                          (acc[mi][2][r] + acc[mi][3][r]);
                #pragma unroll
                for (int o = 8; o >= 1; o >>= 1) s += __shfl_xor(s, o);
                const float mu = s * (1.0f / 64.0f);
                float sq = 0.f;
                #pragma unroll
                for (int ni = 0; ni < 4; ++ni) {
                    const float dv = acc[mi][ni][r] - mu;
                    sq = fmaf(dv, dv, sq);
                }
                #pragma unroll
                for (int o = 8; o >= 1; o >>= 1) sq += __shfl_xor(sq, o);
                const float rstd = rsqrtf(sq * (1.0f / 64.0f) + EPS_);
                // local key k = mi*16 + quad*4 + r in tile wm -> permuted slot
                // s = (quad*4+r)*4 + mi  (key(s) = (s&3)*16 + (s>>2))
                const int np = wm * 64 + quad * 16 + r * 4 + mi;
                #pragma unroll
                for (int ni = 0; ni < 4; ++ni) {
                    const int d = ni * 16 + l15;
                    K16[rowoff + d] = f2b(acc[mi][ni][r]);
                    SMEM[(wn * 64 + ni * 16 + l15) * VS_ + np] =
                        f2b((acc[mi][ni][r] - mu) * rstd * g4[ni] + b4[ni]);
                }
            }
        __syncthreads();
        // coalesced copy-out: rows cl = hl*64 + d (2 heads), cols = block's
        // 128 n-positions (slot-permuted within each 64-tile).
        const int bD  = ((m0 >> 10) * H_ + (c0 >> 6)) * 64;
        const int nbb = m0 & 1023;
        #pragma unroll
        for (int i = 0; i < 8; ++i) {
            const int chunk = tid + 256 * i;        // 0..2047
            const int cl = chunk >> 4, nc = (chunk & 15) * 8;
            *(bf8_t*)&Vt[(size_t)(bD + cl) * N_ + nbb + nc] =
                *(const bf8_t*)&SMEM[cl * VS_ + nc];
        }
    }
}

// ---------------------------------------------------------------------------
// MFMA flash attention, max-free softmax with exp2 (Q pre-scaled by log2e).
// Qs/Ps LDS union (34.8 KB, 4 blocks/CU). XCD-aware 1-D grid: bid = qt*96+bh.
// ---------------------------------------------------------------------------
__global__ __launch_bounds__(256, 4) void attn_mfma(
    const ush* __restrict__ Qh, const ush* __restrict__ Kh,
    const ush* __restrict__ Vt, ush* __restrict__ ATT)
{
    const int bh = blockIdx.x % BH_;
    const int q0 = (blockIdx.x / BH_) * 128;
    const int tid = threadIdx.x;
    const int w = tid >> 6, lane = tid & 63, l15 = lane & 15, quad = lane >> 4;

    __shared__ __align__(16) ush Ks[64 * 64];
    __shared__ __align__(16) ush Vs[64 * 64];     // [d][slot] swizzled
    __shared__ __align__(16) ush QPs[128 * PS_];  // Qs (16KB) then reused as Ps

    const int sw8 = (l15 & 7);

    {
        const char* qg = (const char*)(Qh + ((size_t)bh * N_ + q0) * DH_);
        #pragma unroll
        for (int i = 0; i < 4; ++i) {
            const int slot = (w * 4 + i) * 64 + lane;
            const int row = slot >> 3, cc = (slot & 7) ^ (row & 7);
            gload_lds16(qg + (size_t)row * 128 + cc * 16, (char*)QPs + slot * 16);
        }
    }
    __syncthreads();

    bf8_t aq[2][2];
    #pragma unroll
    for (int mi = 0; mi < 2; ++mi)
        #pragma unroll
        for (int ks = 0; ks < 2; ++ks)
            aq[mi][ks] = *(const bf8_t*)&QPs[(w * 32 + mi * 16 + l15) * 64 +
                                             (((ks * 4 + quad) ^ sw8) * 8)];

    f4_t O[2][4];
    float l_[2][4];
    #pragma unroll
    for (int mi = 0; mi < 2; ++mi)
        #pragma unroll
        for (int r = 0; r < 4; ++r) {
            l_[mi][r] = 0.f;
            #pragma unroll
            for (int ni = 0; ni < 4; ++ni) O[mi][ni][r] = 0.f;
        }

    const char* kg = (const char*)(Kh + (size_t)bh * N_ * DH_);
    const char* vg = (const char*)(Vt + (size_t)bh * DH_ * N_);

    for (int t = 0; t < 16; ++t) {
        __syncthreads();
        #pragma unroll
        for (int i = 0; i < 2; ++i) {
            const int slot = (w * 2 + i) * 64 + lane;
            const int row = slot >> 3, cc = (slot & 7) ^ (row & 7);
            gload_lds16(kg + (size_t)(t * 64 + row) * 128 + cc * 16,
                        (char*)Ks + slot * 16);
            gload_lds16(vg + (size_t)row * (N_ * 2) + t * 128 + cc * 16,
                        (char*)Vs + slot * 16);
        }
        __syncthreads();

        f4_t s[2][4];
        #pragma unroll
        for (int mi = 0; mi < 2; ++mi)
            #pragma unroll
            for (int ni = 0; ni < 4; ++ni)
                #pragma unroll
                for (int r = 0; r < 4; ++r) s[mi][ni][r] = 0.f;
        #pragma unroll
        for (int ks = 0; ks < 2; ++ks)
            #pragma unroll
            for (int ni = 0; ni < 4; ++ni) {
                bf8_t bk = *(const bf8_t*)&Ks[(ni * 16 + l15) * 64 +
                                              (((ks * 4 + quad) ^ sw8) * 8)];
                #pragma unroll
                for (int mi = 0; mi < 2; ++mi)
                    s[mi][ni] = __builtin_amdgcn_mfma_f32_16x16x32_bf16(
                        aq[mi][ks], bk, s[mi][ni], 0, 0, 0);
            }

        if (t == 15) {
            #pragma unroll
            for (int mi = 0; mi < 2; ++mi)
                #pragma unroll
                for (int r = 0; r < 4; ++r) {
                    const int row = q0 + w * 32 + mi * 16 + quad * 4 + r;
                    if (row < CTX_) { s[mi][2][r] = -1e30f; s[mi][3][r] = -1e30f; }
                }
        }

        // max-free softmax via exp2 (scores pre-scaled by log2e); packed P
        #pragma unroll
        for (int mi = 0; mi < 2; ++mi)
            #pragma unroll
            for (int r = 0; r < 4; ++r) {
                float p0 = exp2f(s[mi][0][r]), p1 = exp2f(s[mi][1][r]);
                float p2 = exp2f(s[mi][2][r]), p3 = exp2f(s[mi][3][r]);
                l_[mi][r] += (p0 + p1) + (p2 + p3);
                ushort4 pk;
                pk.x = f2b(p0); pk.y = f2b(p1); pk.z = f2b(p2); pk.w = f2b(p3);
                *(ushort4*)&QPs[(w * 32 + mi * 16 + quad * 4 + r) * PS_ + l15 * 4] = pk;
            }

        #pragma unroll
        for (int ks = 0; ks < 2; ++ks) {
            bf8_t ap[2];
            #pragma unroll
            for (int mi = 0; mi < 2; ++mi)
                ap[mi] = *(const bf8_t*)&QPs[(w * 32 + mi * 16 + l15) * PS_ +
                                             ks * 32 + quad * 8];
            #pragma unroll
            for (int ni = 0; ni < 4; ++ni) {
                bf8_t bv = *(const bf8_t*)&Vs[(ni * 16 + l15) * 64 +
                                              (((ks * 4 + quad) ^ sw8) * 8)];
                #pragma unroll
                for (int mi = 0; mi < 2; ++mi)
                    O[mi][ni] = __builtin_amdgcn_mfma_f32_16x16x32_bf16(
                        ap[mi], bv, O[mi][ni], 0, 0, 0);
            }
        }
    }

    const int b = bh / H_, h = bh % H_;
    #pragma unroll
    for (int mi = 0; mi < 2; ++mi)
        #pragma unroll
        for (int r = 0; r < 4; ++r) {
            float l = l_[mi][r];
            #pragma unroll
            for (int o = 8; o >= 1; o >>= 1) l += __shfl_xor(l, o);
            const float inv = 1.0f / l;
            const int row = q0 + w * 32 + mi * 16 + quad * 4 + r;
            #pragma unroll
            for (int ni = 0; ni < 4; ++ni)
                ATT[((size_t)b * N_ + row) * DIM_ + h * DH_ + ni * 16 + l15] =
                    f2b(O[mi][ni][r] * inv);
        }
}

// ---------------------------------------------------------------------------
// Merged MFMA GEMM: out = ATT @ Wt^T + bias (fp32 out), single dispatch.
// 128x128 tiles. y<64: ctx rows; y>=64: latent tiles.
// ---------------------------------------------------------------------------
__global__ __launch_bounds__(256, 2) void gemm_o_mfma(
    const ush* __restrict__ ATT, const ush* __restrict__ Btc,
    const float* __restrict__ biasc, const ush* __restrict__ Btl,
    const float* __restrict__ biasl, float* __restrict__ out)
{
    const int lat = (blockIdx.y >= 64);
    const ush* Bt     = lat ? Btl : Btc;
    const float* bias = lat ? biasl : biasc;
    const int m0 = (lat ? (blockIdx.y - 64) : blockIdx.y) * 128;
    const int c0 = blockIdx.x * 128;
    const int tid = threadIdx.x;
    const int w = tid >> 6, lane = tid & 63, l15 = lane & 15, quad = lane >> 4;
    const int wm = w >> 1, wn = w & 1;

    __shared__ __align__(16) ush As[128 * 32];
    __shared__ __align__(16) ush Bs[128 * 32];

    const int slot0 = w * 2 * 64 + lane;
    const int srow0 = slot0 >> 2, scc0 = (slot0 & 3) ^ (srow0 & 3);
    const int slot1 = slot0 + 64;
    const int srow1 = slot1 >> 2, scc1 = (slot1 & 3) ^ (srow1 & 3);
    const int am0 = m0 + srow0, am1 = m0 + srow1;
    const int grow0 = lat ? (((am0 >> 5) << 10) + CTX_ + (am0 & 31)) : am0;
    const int grow1 = lat ? (((am1 >> 5) << 10) + CTX_ + (am1 & 31)) : am1;

    f4_t acc[4][4];
    #pragma unroll
    for (int i = 0; i < 4; ++i)
        #pragma unroll
        for (int j = 0; j < 4; ++j)
            #pragma unroll
            for (int r = 0; r < 4; ++r) acc[i][j][r] = 0.f;

    for (int k0 = 0; k0 < DIM_; k0 += 32) {
        __syncthreads();
        gload_lds16((const char*)ATT + (size_t)grow0 * (DIM_ * 2) + k0 * 2 + scc0 * 16,
                    (char*)As + slot0 * 16);
        gload_lds16((const char*)Bt + (size_t)(c0 + srow0) * (DIM_ * 2) + k0 * 2 + scc0 * 16,
                    (char*)Bs + slot0 * 16);
        gload_lds16((const char*)ATT + (size_t)grow1 * (DIM_ * 2) + k0 * 2 + scc1 * 16,
                    (char*)As + slot1 * 16);
        gload_lds16((const char*)Bt + (size_t)(c0 + srow1) * (DIM_ * 2) + k0 * 2 + scc1 * 16,
                    (char*)Bs + slot1 * 16);
        __syncthreads();

        const int sq = (quad ^ (l15 & 3)) * 8;
        bf8_t af[4];
        #pragma unroll
        for (int mi = 0; mi < 4; ++mi)
            af[mi] = *(const bf8_t*)&As[(wm * 64 + mi * 16 + l15) * 32 + sq];
        #pragma unroll
        for (int ni = 0; ni < 4; ++ni) {
            bf8_t bfr = *(const bf8_t*)&Bs[(wn * 64 + ni * 16 + l15) * 32 + sq];
            #pragma unroll
            for (int mi = 0; mi < 4; ++mi)
                acc[mi][ni] = __builtin_amdgcn_mfma_f32_16x16x32_bf16(
                    af[mi], bfr, acc[mi][ni], 0, 0, 0);
        }
    }

    #pragma unroll
    for (int mi = 0; mi < 4; ++mi)
        #pragma unroll
        for (int ni = 0; ni < 4; ++ni) {
            const int c = c0 + wn * 64 + ni * 16 + l15;
            const float bs = bias[c];
            #pragma unroll
            for (int r = 0; r < 4; ++r) {
                const int m = m0 + wm * 64 + mi * 16 + quad * 4 + r;
                if (!lat && (m & 1023) >= CTX_) continue;
                const int grow = lat ? (((m >> 5) << 10) + CTX_ + (m & 31)) : m;
                out[(size_t)grow * DIM_ + c] = acc[mi][ni][r] + bs;
            }
        }
}

// ---------------------------------------------------------------------------
extern "C" void kernel_launch(void* const* d_in, const int* in_sizes, int n_in,
                              void* d_out, int out_size, void* d_ws, size_t ws_size,
                              hipStream_t stream) {
    const float* X      = (const float*)d_in[0];
    const float* Wq     = (const float*)d_in[1];
    const float* Wkv    = (const float*)d_in[2];
    const float* Wo_ctx = (const float*)d_in[3];
    const float* bo_ctx = (const float*)d_in[4];
    const float* Wo_lat = (const float*)d_in[5];
    const float* bo_lat = (const float*)d_in[6];
    const float* ln_g   = (const float*)d_in[7];
    const float* ln_b   = (const float*)d_in[8];
    float* out = (float*)d_out;

    ush* ws = (ush*)d_ws;
    const size_t E = (size_t)BH_ * N_ * DH_;   // 6,291,456
    ush* Xb  = ws;                 // later reused as ATT
    ush* Q16 = ws + E;
    ush* K16 = ws + 2 * E;
    ush* Vt  = ws + 3 * E;
    ush* Wt0 = ws + 4 * E;
    ush* Wt1 = Wt0 + WSZ_;
    ush* Wt2 = Wt1 + WSZ_;
    ush* Wt3 = Wt2 + WSZ_;
    ush* ATT = Xb;                 // alias: Xb dead after gemm_qkv

    cast_all<<<dim3(6144 + 576), 256, 0, stream>>>(X, Xb, Wq, Wkv, Wo_ctx,
                                                   Wo_lat, Wt0, Wt1, Wt2, Wt3);
    gemm_qkv_mfma<<<dim3(6, 64, 2), 256, 0, stream>>>(Xb, Wt0, Wt1, Q16, K16,
                                                      Vt, ln_g, ln_b);
    attn_mfma<<<dim3(8 * BH_), 256, 0, stream>>>(Q16, K16, Vt, ATT);
    gemm_o_mfma<<<dim3(6, 66), 256, 0, stream>>>(ATT, Wt2, bo_ctx, Wt3, bo_lat, out);
}

// Round 12
// 193.314 us; speedup vs baseline: 1.0648x; 1.0648x over previous
//
#include <hip/hip_runtime.h>

#define B_    8
#define N_    1024
#define DIM_  768
#define H_    12
#define DH_   64
#define CTX_  992
#define BH_   (B_ * H_)
#define EPS_  1e-5f
#define WSZ_  (DIM_ * DIM_)
#define PS_   72    // attn Ps row stride (ush)
#define VS_   136   // gemm_qkv VT overlay row stride (ush): 128 cols + 8 pad

typedef unsigned short ush;
typedef __attribute__((ext_vector_type(8))) short bf8_t;   // 8 bf16 (A/B frag)
typedef __attribute__((ext_vector_type(4))) float f4_t;    // 4 fp32 (C/D frag)

__device__ __forceinline__ float b2f(ush u) {
    return __uint_as_float(((unsigned)u) << 16);
}
__device__ __forceinline__ ush f2b(float f) {   // round-to-nearest-even
    unsigned u = __float_as_uint(f);
    u += 0x7fffu + ((u >> 16) & 1u);
    return (ush)(u >> 16);
}
__device__ __forceinline__ float fexp2(float x) {   // bare v_exp_f32, no guards
    return __builtin_amdgcn_exp2f(x);
}
__device__ __forceinline__ void gload_lds16(const void* g, void* l) {
    __builtin_amdgcn_global_load_lds(
        (const __attribute__((address_space(1))) void*)g,
        (__attribute__((address_space(3))) void*)l, 16, 0, 0);
}

// ---------------------------------------------------------------------------
// Merged cast kernel: blocks [0, 6144) cast X fp32->bf16; blocks [6144, 6720)
// transpose+cast the four 768x768 weights (bf16 Wt[n][k] = W[k][n]).
// ---------------------------------------------------------------------------
__global__ __launch_bounds__(256) void cast_all(
    const float* __restrict__ X, ush* __restrict__ Xb,
    const float* __restrict__ W0, const float* __restrict__ W1,
    const float* __restrict__ W2, const float* __restrict__ W3,
    ush* __restrict__ T0, ush* __restrict__ T1,
    ush* __restrict__ T2, ush* __restrict__ T3)
{
    __shared__ ush T[64][65];
    const int bid = blockIdx.x;
    const int tid = threadIdx.x;

    if (bid < 6144) {
        const int i4 = bid * 256 + tid;      // float4 index
        float4 v = *(const float4*)&X[(size_t)i4 * 4];
        ushort4 o;
        o.x = f2b(v.x); o.y = f2b(v.y); o.z = f2b(v.z); o.w = f2b(v.w);
        *(ushort4*)&Xb[(size_t)i4 * 4] = o;
        return;
    }
    const int t = bid - 6144;                // 0..575
    const int z = t / 144, rem = t % 144;
    const int i0 = (rem / 12) * 64;          // k-rows
    const int j0 = (rem % 12) * 64;          // n-cols
    const float* W = (z == 0) ? W0 : (z == 1) ? W1 : (z == 2) ? W2 : W3;
    ush* Wt        = (z == 0) ? T0 : (z == 1) ? T1 : (z == 2) ? T2 : T3;

    const int r4 = tid >> 4, c = (tid & 15) << 2;
    #pragma unroll
    for (int g = 0; g < 4; ++g) {
        const int r = r4 + g * 16;
        float4 v = *(const float4*)&W[(size_t)(i0 + r) * DIM_ + j0 + c];
        T[r][c + 0] = f2b(v.x); T[r][c + 1] = f2b(v.y);
        T[r][c + 2] = f2b(v.z); T[r][c + 3] = f2b(v.w);
    }
    __syncthreads();
    const int nl = tid >> 2, k0l = (tid & 3) << 4;
    #pragma unroll
    for (int g = 0; g < 4; ++g) {
        ushort4 o;
        o.x = T[k0l + 4 * g + 0][nl]; o.y = T[k0l + 4 * g + 1][nl];
        o.z = T[k0l + 4 * g + 2][nl]; o.w = T[k0l + 4 * g + 3][nl];
        *(ushort4*)&Wt[(size_t)(j0 + nl) * DIM_ + i0 + k0l + 4 * g] = o;
    }
}

// ---------------------------------------------------------------------------
// Fused MFMA GEMM + RoPE (+scale for Q; +LN for KV) + V-transpose.
// Tile 128x128, BK=32, XOR-swizzled LDS. z=0: Q16 = rope(acc)*0.125*log2e
// (attn uses exp2). z=1: K16 = rope(acc); LN'd V transposed block-locally
// through an LDS overlay [128 d-rows][VS_] (slot-permuted to match attn's
// packed-P order) then copied out coalesced -> Vt[bh][d][n].
// ---------------------------------------------------------------------------
__global__ __launch_bounds__(256, 3) void gemm_qkv_mfma(
    const ush* __restrict__ Xb, const ush* __restrict__ Wt0,
    const ush* __restrict__ Wt1, ush* __restrict__ Q16, ush* __restrict__ K16,
    ush* __restrict__ Vt, const float* __restrict__ ln_g,
    const float* __restrict__ ln_b)
{
    const int z   = blockIdx.z;
    const ush* Bt = z ? Wt1 : Wt0;
    const int m0 = blockIdx.y * 128, c0 = blockIdx.x * 128;
    const int tid = threadIdx.x;
    const int w = tid >> 6, lane = tid & 63, l15 = lane & 15, quad = lane >> 4;
    const int wm = w >> 1, wn = w & 1;

    __shared__ __align__(16) ush SMEM[128 * VS_];
    ush* As = SMEM;
    ush* Bs = SMEM + 4096;

    const int slot0 = w * 2 * 64 + lane;
    const int srow0 = slot0 >> 2, scc0 = (slot0 & 3) ^ (srow0 & 3);
    const int slot1 = slot0 + 64;
    const int srow1 = slot1 >> 2, scc1 = (slot1 & 3) ^ (srow1 & 3);

    f4_t acc[4][4];
    #pragma unroll
    for (int i = 0; i < 4; ++i)
        #pragma unroll
        for (int j = 0; j < 4; ++j)
            #pragma unroll
            for (int r = 0; r < 4; ++r) acc[i][j][r] = 0.f;

    for (int k0 = 0; k0 < DIM_; k0 += 32) {
        __syncthreads();
        gload_lds16((const char*)Xb + (size_t)(m0 + srow0) * (DIM_ * 2) + k0 * 2 + scc0 * 16,
                    (char*)As + slot0 * 16);
        gload_lds16((const char*)Bt + (size_t)(c0 + srow0) * (DIM_ * 2) + k0 * 2 + scc0 * 16,
                    (char*)Bs + slot0 * 16);
        gload_lds16((const char*)Xb + (size_t)(m0 + srow1) * (DIM_ * 2) + k0 * 2 + scc1 * 16,
                    (char*)As + slot1 * 16);
        gload_lds16((const char*)Bt + (size_t)(c0 + srow1) * (DIM_ * 2) + k0 * 2 + scc1 * 16,
                    (char*)Bs + slot1 * 16);
        __syncthreads();

        const int sq = (quad ^ (l15 & 3)) * 8;
        bf8_t af[4];
        #pragma unroll
        for (int mi = 0; mi < 4; ++mi)
            af[mi] = *(const bf8_t*)&As[(wm * 64 + mi * 16 + l15) * 32 + sq];
        #pragma unroll
        for (int ni = 0; ni < 4; ++ni) {
            bf8_t bfr = *(const bf8_t*)&Bs[(wn * 64 + ni * 16 + l15) * 32 + sq];
            #pragma unroll
            for (int mi = 0; mi < 4; ++mi)
                acc[mi][ni] = __builtin_amdgcn_mfma_f32_16x16x32_bf16(
                    af[mi], bfr, acc[mi][ni], 0, 0, 0);
        }
    }

    // ---- fused RoPE epilogue ----
    const float inv0 = __expf(-(float)l15 * (9.210340371976184f / 32.0f));
    const float inv1 = inv0 * 0.01f;    // 10000^(-16/32)
    const int h  = (c0 >> 6) + wn;
    const int b  = (m0 + wm * 64) >> 10;
    const int nb = (m0 + wm * 64) & 1023;

    #pragma unroll
    for (int mi = 0; mi < 4; ++mi) {
        #pragma unroll
        for (int r = 0; r < 4; ++r) {
            const int n = nb + mi * 16 + quad * 4 + r;
            float sn0, cs0, sn1, cs1;
            __sincosf((float)n * inv0, &sn0, &cs0);
            __sincosf((float)n * inv1, &sn1, &cs1);
            {
                float a = acc[mi][0][r], p = acc[mi][2][r];
                acc[mi][0][r] = a * cs0 - p * sn0;
                acc[mi][2][r] = p * cs0 + a * sn0;
            }
            {
                float a = acc[mi][1][r], p = acc[mi][3][r];
                acc[mi][1][r] = a * cs1 - p * sn1;
                acc[mi][3][r] = p * cs1 + a * sn1;
            }
        }
    }

    if (z == 0) {
        // Q path: scale by DH^-0.5 * log2(e) so attn can use exp2 directly
        #pragma unroll
        for (int mi = 0; mi < 4; ++mi)
            #pragma unroll
            for (int ni = 0; ni < 4; ++ni)
                #pragma unroll
                for (int r = 0; r < 4; ++r) {
                    const int n = nb + mi * 16 + quad * 4 + r;
                    const int d = ni * 16 + l15;
                    Q16[(((size_t)b * H_ + h) * N_ + n) * DH_ + d] =
                        f2b(acc[mi][ni][r] * 0.1803368801111731f);
                }
    } else {
        float g4[4], b4[4];
        #pragma unroll
        for (int ni = 0; ni < 4; ++ni) {
            g4[ni] = ln_g[ni * 16 + l15];
            b4[ni] = ln_b[ni * 16 + l15];
        }
        __syncthreads();   // all waves done with As/Bs -> VT overlay is safe
        #pragma unroll
        for (int mi = 0; mi < 4; ++mi)
            #pragma unroll
            for (int r = 0; r < 4; ++r) {
                const int n = nb + mi * 16 + quad * 4 + r;
                const size_t rowoff = (((size_t)b * H_ + h) * N_ + n) * DH_;
                float s = (acc[mi][0][r] + acc[mi][1][r]) +
                          (acc[mi][2][r] + acc[mi][3][r]);
                #pragma unroll
                for (int o = 8; o >= 1; o >>= 1) s += __shfl_xor(s, o);
                const float mu = s * (1.0f / 64.0f);
                float sq = 0.f;
                #pragma unroll
                for (int ni = 0; ni < 4; ++ni) {
                    const float dv = acc[mi][ni][r] - mu;
                    sq = fmaf(dv, dv, sq);
                }
                #pragma unroll
                for (int o = 8; o >= 1; o >>= 1) sq += __shfl_xor(sq, o);
                const float rstd = rsqrtf(sq * (1.0f / 64.0f) + EPS_);
                // local key k = mi*16 + quad*4 + r in tile wm -> permuted slot
                // s = (quad*4+r)*4 + mi  (key(s) = (s&3)*16 + (s>>2))
                const int np = wm * 64 + quad * 16 + r * 4 + mi;
                #pragma unroll
                for (int ni = 0; ni < 4; ++ni) {
                    const int d = ni * 16 + l15;
                    K16[rowoff + d] = f2b(acc[mi][ni][r]);
                    SMEM[(wn * 64 + ni * 16 + l15) * VS_ + np] =
                        f2b((acc[mi][ni][r] - mu) * rstd * g4[ni] + b4[ni]);
                }
            }
        __syncthreads();
        const int bD  = ((m0 >> 10) * H_ + (c0 >> 6)) * 64;
        const int nbb = m0 & 1023;
        #pragma unroll
        for (int i = 0; i < 8; ++i) {
            const int chunk = tid + 256 * i;        // 0..2047
            const int cl = chunk >> 4, nc = (chunk & 15) * 8;
            *(bf8_t*)&Vt[(size_t)(bD + cl) * N_ + nbb + nc] =
                *(const bf8_t*)&SMEM[cl * VS_ + nc];
        }
    }
}

// ---------------------------------------------------------------------------
// MFMA flash attention, max-free softmax via bare v_exp_f32 (Q pre-scaled by
// log2e). Qs/Ps LDS union (34.8 KB, 4 blocks/CU). XCD-aware 1-D grid.
// ---------------------------------------------------------------------------
__global__ __launch_bounds__(256, 4) void attn_mfma(
    const ush* __restrict__ Qh, const ush* __restrict__ Kh,
    const ush* __restrict__ Vt, ush* __restrict__ ATT)
{
    const int bh = blockIdx.x % BH_;
    const int q0 = (blockIdx.x / BH_) * 128;
    const int tid = threadIdx.x;
    const int w = tid >> 6, lane = tid & 63, l15 = lane & 15, quad = lane >> 4;

    __shared__ __align__(16) ush Ks[64 * 64];
    __shared__ __align__(16) ush Vs[64 * 64];     // [d][slot] swizzled
    __shared__ __align__(16) ush QPs[128 * PS_];  // Qs (16KB) then reused as Ps

    const int sw8 = (l15 & 7);

    {
        const char* qg = (const char*)(Qh + ((size_t)bh * N_ + q0) * DH_);
        #pragma unroll
        for (int i = 0; i < 4; ++i) {
            const int slot = (w * 4 + i) * 64 + lane;
            const int row = slot >> 3, cc = (slot & 7) ^ (row & 7);
            gload_lds16(qg + (size_t)row * 128 + cc * 16, (char*)QPs + slot * 16);
        }
    }
    __syncthreads();

    bf8_t aq[2][2];
    #pragma unroll
    for (int mi = 0; mi < 2; ++mi)
        #pragma unroll
        for (int ks = 0; ks < 2; ++ks)
            aq[mi][ks] = *(const bf8_t*)&QPs[(w * 32 + mi * 16 + l15) * 64 +
                                             (((ks * 4 + quad) ^ sw8) * 8)];

    f4_t O[2][4];
    float l_[2][4];
    #pragma unroll
    for (int mi = 0; mi < 2; ++mi)
        #pragma unroll
        for (int r = 0; r < 4; ++r) {
            l_[mi][r] = 0.f;
            #pragma unroll
            for (int ni = 0; ni < 4; ++ni) O[mi][ni][r] = 0.f;
        }

    const char* kg = (const char*)(Kh + (size_t)bh * N_ * DH_);
    const char* vg = (const char*)(Vt + (size_t)bh * DH_ * N_);

    for (int t = 0; t < 16; ++t) {
        __syncthreads();
        #pragma unroll
        for (int i = 0; i < 2; ++i) {
            const int slot = (w * 2 + i) * 64 + lane;
            const int row = slot >> 3, cc = (slot & 7) ^ (row & 7);
            gload_lds16(kg + (size_t)(t * 64 + row) * 128 + cc * 16,
                        (char*)Ks + slot * 16);
            gload_lds16(vg + (size_t)row * (N_ * 2) + t * 128 + cc * 16,
                        (char*)Vs + slot * 16);
        }
        __syncthreads();

        f4_t s[2][4];
        #pragma unroll
        for (int mi = 0; mi < 2; ++mi)
            #pragma unroll
            for (int ni = 0; ni < 4; ++ni)
                #pragma unroll
                for (int r = 0; r < 4; ++r) s[mi][ni][r] = 0.f;
        #pragma unroll
        for (int ks = 0; ks < 2; ++ks)
            #pragma unroll
            for (int ni = 0; ni < 4; ++ni) {
                bf8_t bk = *(const bf8_t*)&Ks[(ni * 16 + l15) * 64 +
                                              (((ks * 4 + quad) ^ sw8) * 8)];
                #pragma unroll
                for (int mi = 0; mi < 2; ++mi)
                    s[mi][ni] = __builtin_amdgcn_mfma_f32_16x16x32_bf16(
                        aq[mi][ks], bk, s[mi][ni], 0, 0, 0);
            }

        if (t == 15) {
            #pragma unroll
            for (int mi = 0; mi < 2; ++mi)
                #pragma unroll
                for (int r = 0; r < 4; ++r) {
                    const int row = q0 + w * 32 + mi * 16 + quad * 4 + r;
                    if (row < CTX_) { s[mi][2][r] = -1e30f; s[mi][3][r] = -1e30f; }
                }
        }

        // max-free softmax via bare v_exp_f32; packed P (slot s = l15*4 + ni)
        #pragma unroll
        for (int mi = 0; mi < 2; ++mi)
            #pragma unroll
            for (int r = 0; r < 4; ++r) {
                float p0 = fexp2(s[mi][0][r]), p1 = fexp2(s[mi][1][r]);
                float p2 = fexp2(s[mi][2][r]), p3 = fexp2(s[mi][3][r]);
                l_[mi][r] += (p0 + p1) + (p2 + p3);
                ushort4 pk;
                pk.x = f2b(p0); pk.y = f2b(p1); pk.z = f2b(p2); pk.w = f2b(p3);
                *(ushort4*)&QPs[(w * 32 + mi * 16 + quad * 4 + r) * PS_ + l15 * 4] = pk;
            }

        #pragma unroll
        for (int ks = 0; ks < 2; ++ks) {
            bf8_t ap[2];
            #pragma unroll
            for (int mi = 0; mi < 2; ++mi)
                ap[mi] = *(const bf8_t*)&QPs[(w * 32 + mi * 16 + l15) * PS_ +
                                             ks * 32 + quad * 8];
            #pragma unroll
            for (int ni = 0; ni < 4; ++ni) {
                bf8_t bv = *(const bf8_t*)&Vs[(ni * 16 + l15) * 64 +
                                              (((ks * 4 + quad) ^ sw8) * 8)];
                #pragma unroll
                for (int mi = 0; mi < 2; ++mi)
                    O[mi][ni] = __builtin_amdgcn_mfma_f32_16x16x32_bf16(
                        ap[mi], bv, O[mi][ni], 0, 0, 0);
            }
        }
    }

    const int b = bh / H_, h = bh % H_;
    #pragma unroll
    for (int mi = 0; mi < 2; ++mi)
        #pragma unroll
        for (int r = 0; r < 4; ++r) {
            float l = l_[mi][r];
            #pragma unroll
            for (int o = 8; o >= 1; o >>= 1) l += __shfl_xor(l, o);
            const float inv = 1.0f / l;
            const int row = q0 + w * 32 + mi * 16 + quad * 4 + r;
            #pragma unroll
            for (int ni = 0; ni < 4; ++ni)
                ATT[((size_t)b * N_ + row) * DIM_ + h * DH_ + ni * 16 + l15] =
                    f2b(O[mi][ni][r] * inv);
        }
}

// ---------------------------------------------------------------------------
// Merged MFMA GEMM: out = ATT @ Wt^T + bias (fp32 out), single dispatch.
// 128x128 tiles. y<64: ctx rows; y>=64: latent tiles.
// ---------------------------------------------------------------------------
__global__ __launch_bounds__(256, 2) void gemm_o_mfma(
    const ush* __restrict__ ATT, const ush* __restrict__ Btc,
    const float* __restrict__ biasc, const ush* __restrict__ Btl,
    const float* __restrict__ biasl, float* __restrict__ out)
{
    const int lat = (blockIdx.y >= 64);
    const ush* Bt     = lat ? Btl : Btc;
    const float* bias = lat ? biasl : biasc;
    const int m0 = (lat ? (blockIdx.y - 64) : blockIdx.y) * 128;
    const int c0 = blockIdx.x * 128;
    const int tid = threadIdx.x;
    const int w = tid >> 6, lane = tid & 63, l15 = lane & 15, quad = lane >> 4;
    const int wm = w >> 1, wn = w & 1;

    __shared__ __align__(16) ush As[128 * 32];
    __shared__ __align__(16) ush Bs[128 * 32];

    const int slot0 = w * 2 * 64 + lane;
    const int srow0 = slot0 >> 2, scc0 = (slot0 & 3) ^ (srow0 & 3);
    const int slot1 = slot0 + 64;
    const int srow1 = slot1 >> 2, scc1 = (slot1 & 3) ^ (srow1 & 3);
    const int am0 = m0 + srow0, am1 = m0 + srow1;
    const int grow0 = lat ? (((am0 >> 5) << 10) + CTX_ + (am0 & 31)) : am0;
    const int grow1 = lat ? (((am1 >> 5) << 10) + CTX_ + (am1 & 31)) : am1;

    f4_t acc[4][4];
    #pragma unroll
    for (int i = 0; i < 4; ++i)
        #pragma unroll
        for (int j = 0; j < 4; ++j)
            #pragma unroll
            for (int r = 0; r < 4; ++r) acc[i][j][r] = 0.f;

    for (int k0 = 0; k0 < DIM_; k0 += 32) {
        __syncthreads();
        gload_lds16((const char*)ATT + (size_t)grow0 * (DIM_ * 2) + k0 * 2 + scc0 * 16,
                    (char*)As + slot0 * 16);
        gload_lds16((const char*)Bt + (size_t)(c0 + srow0) * (DIM_ * 2) + k0 * 2 + scc0 * 16,
                    (char*)Bs + slot0 * 16);
        gload_lds16((const char*)ATT + (size_t)grow1 * (DIM_ * 2) + k0 * 2 + scc1 * 16,
                    (char*)As + slot1 * 16);
        gload_lds16((const char*)Bt + (size_t)(c0 + srow1) * (DIM_ * 2) + k0 * 2 + scc1 * 16,
                    (char*)Bs + slot1 * 16);
        __syncthreads();

        const int sq = (quad ^ (l15 & 3)) * 8;
        bf8_t af[4];
        #pragma unroll
        for (int mi = 0; mi < 4; ++mi)
            af[mi] = *(const bf8_t*)&As[(wm * 64 + mi * 16 + l15) * 32 + sq];
        #pragma unroll
        for (int ni = 0; ni < 4; ++ni) {
            bf8_t bfr = *(const bf8_t*)&Bs[(wn * 64 + ni * 16 + l15) * 32 + sq];
            #pragma unroll
            for (int mi = 0; mi < 4; ++mi)
                acc[mi][ni] = __builtin_amdgcn_mfma_f32_16x16x32_bf16(
                    af[mi], bfr, acc[mi][ni], 0, 0, 0);
        }
    }

    #pragma unroll
    for (int mi = 0; mi < 4; ++mi)
        #pragma unroll
        for (int ni = 0; ni < 4; ++ni) {
            const int c = c0 + wn * 64 + ni * 16 + l15;
            const float bs = bias[c];
            #pragma unroll
            for (int r = 0; r < 4; ++r) {
                const int m = m0 + wm * 64 + mi * 16 + quad * 4 + r;
                if (!lat && (m & 1023) >= CTX_) continue;
                const int grow = lat ? (((m >> 5) << 10) + CTX_ + (m & 31)) : m;
                out[(size_t)grow * DIM_ + c] = acc[mi][ni][r] + bs;
            }
        }
}

// ---------------------------------------------------------------------------
extern "C" void kernel_launch(void* const* d_in, const int* in_sizes, int n_in,
                              void* d_out, int out_size, void* d_ws, size_t ws_size,
                              hipStream_t stream) {
    const float* X      = (const float*)d_in[0];
    const float* Wq     = (const float*)d_in[1];
    const float* Wkv    = (const float*)d_in[2];
    const float* Wo_ctx = (const float*)d_in[3];
    const float* bo_ctx = (const float*)d_in[4];
    const float* Wo_lat = (const float*)d_in[5];
    const float* bo_lat = (const float*)d_in[6];
    const float* ln_g   = (const float*)d_in[7];
    const float* ln_b   = (const float*)d_in[8];
    float* out = (float*)d_out;

    ush* ws = (ush*)d_ws;
    const size_t E = (size_t)BH_ * N_ * DH_;   // 6,291,456
    ush* Xb  = ws;                 // later reused as ATT
    ush* Q16 = ws + E;
    ush* K16 = ws + 2 * E;
    ush* Vt  = ws + 3 * E;
    ush* Wt0 = ws + 4 * E;
    ush* Wt1 = Wt0 + WSZ_;
    ush* Wt2 = Wt1 + WSZ_;
    ush* Wt3 = Wt2 + WSZ_;
    ush* ATT = Xb;                 // alias: Xb dead after gemm_qkv

    cast_all<<<dim3(6144 + 576), 256, 0, stream>>>(X, Xb, Wq, Wkv, Wo_ctx,
                                                   Wo_lat, Wt0, Wt1, Wt2, Wt3);
    gemm_qkv_mfma<<<dim3(6, 64, 2), 256, 0, stream>>>(Xb, Wt0, Wt1, Q16, K16,
                                                      Vt, ln_g, ln_b);
    attn_mfma<<<dim3(8 * BH_), 256, 0, stream>>>(Q16, K16, Vt, ATT);
    gemm_o_mfma<<<dim3(6, 66), 256, 0, stream>>>(ATT, Wt2, bo_ctx, Wt3, bo_lat, out);
}

// Round 13
// 187.212 us; speedup vs baseline: 1.0995x; 1.0326x over previous
//
#include <hip/hip_runtime.h>

#define B_    8
#define N_    1024
#define DIM_  768
#define H_    12
#define DH_   64
#define CTX_  992
#define BH_   (B_ * H_)
#define EPS_  1e-5f
#define WSZ_  (DIM_ * DIM_)
#define PS_   72    // attn Ps row stride (ush)
#define VS_   136   // gemm_qkv VT overlay row stride (ush): 128 cols + 8 pad

typedef unsigned short ush;
typedef __attribute__((ext_vector_type(8))) short bf8_t;   // 8 bf16 (A/B frag)
typedef __attribute__((ext_vector_type(4))) float f4_t;    // 4 fp32 (C/D frag)

__device__ __forceinline__ float b2f(ush u) {
    return __uint_as_float(((unsigned)u) << 16);
}
__device__ __forceinline__ ush f2b(float f) {   // round-to-nearest-even
    unsigned u = __float_as_uint(f);
    u += 0x7fffu + ((u >> 16) & 1u);
    return (ush)(u >> 16);
}
__device__ __forceinline__ float fexp2(float x) {   // bare v_exp_f32, no guards
    return __builtin_amdgcn_exp2f(x);
}
__device__ __forceinline__ void gload_lds16(const void* g, void* l) {
    __builtin_amdgcn_global_load_lds(
        (const __attribute__((address_space(1))) void*)g,
        (__attribute__((address_space(3))) void*)l, 16, 0, 0);
}

// ---------------------------------------------------------------------------
// Merged cast kernel: blocks [0, 6144) cast X fp32->bf16; blocks [6144, 6720)
// transpose+cast the four 768x768 weights (bf16 Wt[n][k] = W[k][n]).
// ---------------------------------------------------------------------------
__global__ __launch_bounds__(256) void cast_all(
    const float* __restrict__ X, ush* __restrict__ Xb,
    const float* __restrict__ W0, const float* __restrict__ W1,
    const float* __restrict__ W2, const float* __restrict__ W3,
    ush* __restrict__ T0, ush* __restrict__ T1,
    ush* __restrict__ T2, ush* __restrict__ T3)
{
    __shared__ ush T[64][65];
    const int bid = blockIdx.x;
    const int tid = threadIdx.x;

    if (bid < 6144) {
        const int i4 = bid * 256 + tid;      // float4 index
        float4 v = *(const float4*)&X[(size_t)i4 * 4];
        ushort4 o;
        o.x = f2b(v.x); o.y = f2b(v.y); o.z = f2b(v.z); o.w = f2b(v.w);
        *(ushort4*)&Xb[(size_t)i4 * 4] = o;
        return;
    }
    const int t = bid - 6144;                // 0..575
    const int z = t / 144, rem = t % 144;
    const int i0 = (rem / 12) * 64;          // k-rows
    const int j0 = (rem % 12) * 64;          // n-cols
    const float* W = (z == 0) ? W0 : (z == 1) ? W1 : (z == 2) ? W2 : W3;
    ush* Wt        = (z == 0) ? T0 : (z == 1) ? T1 : (z == 2) ? T2 : T3;

    const int r4 = tid >> 4, c = (tid & 15) << 2;
    #pragma unroll
    for (int g = 0; g < 4; ++g) {
        const int r = r4 + g * 16;
        float4 v = *(const float4*)&W[(size_t)(i0 + r) * DIM_ + j0 + c];
        T[r][c + 0] = f2b(v.x); T[r][c + 1] = f2b(v.y);
        T[r][c + 2] = f2b(v.z); T[r][c + 3] = f2b(v.w);
    }
    __syncthreads();
    const int nl = tid >> 2, k0l = (tid & 3) << 4;
    #pragma unroll
    for (int g = 0; g < 4; ++g) {
        ushort4 o;
        o.x = T[k0l + 4 * g + 0][nl]; o.y = T[k0l + 4 * g + 1][nl];
        o.z = T[k0l + 4 * g + 2][nl]; o.w = T[k0l + 4 * g + 3][nl];
        *(ushort4*)&Wt[(size_t)(j0 + nl) * DIM_ + i0 + k0l + 4 * g] = o;
    }
}

// ---------------------------------------------------------------------------
// Fused MFMA GEMM + RoPE (+scale for Q; +LN for KV) + V-transpose.
// Tile 128x128, BK=64 (half the barriers of BK=32 — thin-K GEMM is
// barrier-drain bound), XOR-swizzled LDS (8 chunks/row, cc^(row&7)).
// z=0: Q16 = rope(acc)*0.125*log2e. z=1: K16 = rope(acc); LN'd V transposed
// block-locally through the LDS overlay (slot-permuted to attn's packed-P
// order) -> Vt[bh][d][n].
// ---------------------------------------------------------------------------
__global__ __launch_bounds__(256, 3) void gemm_qkv_mfma(
    const ush* __restrict__ Xb, const ush* __restrict__ Wt0,
    const ush* __restrict__ Wt1, ush* __restrict__ Q16, ush* __restrict__ K16,
    ush* __restrict__ Vt, const float* __restrict__ ln_g,
    const float* __restrict__ ln_b)
{
    const int z   = blockIdx.z;
    const ush* Bt = z ? Wt1 : Wt0;
    const int m0 = blockIdx.y * 128, c0 = blockIdx.x * 128;
    const int tid = threadIdx.x;
    const int w = tid >> 6, lane = tid & 63, l15 = lane & 15, quad = lane >> 4;
    const int wm = w >> 1, wn = w & 1;

    // SMEM union: As = [0,8192), Bs = [8192,16384) ush during k-loop (32 KB);
    // VT overlay [128][VS_] = 17408 ush (34.8 KB) after the loop (z=1 only).
    __shared__ __align__(16) ush SMEM[128 * VS_];
    ush* As = SMEM;
    ush* Bs = SMEM + 8192;

    const int sw8 = l15 & 7;

    f4_t acc[4][4];
    #pragma unroll
    for (int i = 0; i < 4; ++i)
        #pragma unroll
        for (int j = 0; j < 4; ++j)
            #pragma unroll
            for (int r = 0; r < 4; ++r) acc[i][j][r] = 0.f;

    for (int k0 = 0; k0 < DIM_; k0 += 64) {
        __syncthreads();
        #pragma unroll
        for (int i = 0; i < 4; ++i) {
            const int slot = i * 256 + tid;          // 0..1023
            const int row = slot >> 3, cc = (slot & 7) ^ (row & 7);
            gload_lds16((const char*)Xb + (size_t)(m0 + row) * (DIM_ * 2) + k0 * 2 + cc * 16,
                        (char*)As + slot * 16);
            gload_lds16((const char*)Bt + (size_t)(c0 + row) * (DIM_ * 2) + k0 * 2 + cc * 16,
                        (char*)Bs + slot * 16);
        }
        __syncthreads();

        #pragma unroll
        for (int ks = 0; ks < 2; ++ks) {
            bf8_t af[4];
            #pragma unroll
            for (int mi = 0; mi < 4; ++mi)
                af[mi] = *(const bf8_t*)&As[(wm * 64 + mi * 16 + l15) * 64 +
                                            (((ks * 4 + quad) ^ sw8) * 8)];
            #pragma unroll
            for (int ni = 0; ni < 4; ++ni) {
                bf8_t bfr = *(const bf8_t*)&Bs[(wn * 64 + ni * 16 + l15) * 64 +
                                               (((ks * 4 + quad) ^ sw8) * 8)];
                #pragma unroll
                for (int mi = 0; mi < 4; ++mi)
                    acc[mi][ni] = __builtin_amdgcn_mfma_f32_16x16x32_bf16(
                        af[mi], bfr, acc[mi][ni], 0, 0, 0);
            }
        }
    }

    // ---- fused RoPE epilogue ----
    const float inv0 = __expf(-(float)l15 * (9.210340371976184f / 32.0f));
    const float inv1 = inv0 * 0.01f;    // 10000^(-16/32)
    const int h  = (c0 >> 6) + wn;
    const int b  = (m0 + wm * 64) >> 10;
    const int nb = (m0 + wm * 64) & 1023;

    #pragma unroll
    for (int mi = 0; mi < 4; ++mi) {
        #pragma unroll
        for (int r = 0; r < 4; ++r) {
            const int n = nb + mi * 16 + quad * 4 + r;
            float sn0, cs0, sn1, cs1;
            __sincosf((float)n * inv0, &sn0, &cs0);
            __sincosf((float)n * inv1, &sn1, &cs1);
            {
                float a = acc[mi][0][r], p = acc[mi][2][r];
                acc[mi][0][r] = a * cs0 - p * sn0;
                acc[mi][2][r] = p * cs0 + a * sn0;
            }
            {
                float a = acc[mi][1][r], p = acc[mi][3][r];
                acc[mi][1][r] = a * cs1 - p * sn1;
                acc[mi][3][r] = p * cs1 + a * sn1;
            }
        }
    }

    if (z == 0) {
        // Q path: scale by DH^-0.5 * log2(e) so attn can use exp2 directly
        #pragma unroll
        for (int mi = 0; mi < 4; ++mi)
            #pragma unroll
            for (int ni = 0; ni < 4; ++ni)
                #pragma unroll
                for (int r = 0; r < 4; ++r) {
                    const int n = nb + mi * 16 + quad * 4 + r;
                    const int d = ni * 16 + l15;
                    Q16[(((size_t)b * H_ + h) * N_ + n) * DH_ + d] =
                        f2b(acc[mi][ni][r] * 0.1803368801111731f);
                }
    } else {
        float g4[4], b4[4];
        #pragma unroll
        for (int ni = 0; ni < 4; ++ni) {
            g4[ni] = ln_g[ni * 16 + l15];
            b4[ni] = ln_b[ni * 16 + l15];
        }
        __syncthreads();   // all waves done with As/Bs -> VT overlay is safe
        #pragma unroll
        for (int mi = 0; mi < 4; ++mi)
            #pragma unroll
            for (int r = 0; r < 4; ++r) {
                const int n = nb + mi * 16 + quad * 4 + r;
                const size_t rowoff = (((size_t)b * H_ + h) * N_ + n) * DH_;
                float s = (acc[mi][0][r] + acc[mi][1][r]) +
                          (acc[mi][2][r] + acc[mi][3][r]);
                #pragma unroll
                for (int o = 8; o >= 1; o >>= 1) s += __shfl_xor(s, o);
                const float mu = s * (1.0f / 64.0f);
                float sq = 0.f;
                #pragma unroll
                for (int ni = 0; ni < 4; ++ni) {
                    const float dv = acc[mi][ni][r] - mu;
                    sq = fmaf(dv, dv, sq);
                }
                #pragma unroll
                for (int o = 8; o >= 1; o >>= 1) sq += __shfl_xor(sq, o);
                const float rstd = rsqrtf(sq * (1.0f / 64.0f) + EPS_);
                // local key k = mi*16 + quad*4 + r in tile wm -> permuted slot
                // s = (quad*4+r)*4 + mi  (key(s) = (s&3)*16 + (s>>2))
                const int np = wm * 64 + quad * 16 + r * 4 + mi;
                #pragma unroll
                for (int ni = 0; ni < 4; ++ni) {
                    const int d = ni * 16 + l15;
                    K16[rowoff + d] = f2b(acc[mi][ni][r]);
                    SMEM[(wn * 64 + ni * 16 + l15) * VS_ + np] =
                        f2b((acc[mi][ni][r] - mu) * rstd * g4[ni] + b4[ni]);
                }
            }
        __syncthreads();
        const int bD  = ((m0 >> 10) * H_ + (c0 >> 6)) * 64;
        const int nbb = m0 & 1023;
        #pragma unroll
        for (int i = 0; i < 8; ++i) {
            const int chunk = tid + 256 * i;        // 0..2047
            const int cl = chunk >> 4, nc = (chunk & 15) * 8;
            *(bf8_t*)&Vt[(size_t)(bD + cl) * N_ + nbb + nc] =
                *(const bf8_t*)&SMEM[cl * VS_ + nc];
        }
    }
}

// ---------------------------------------------------------------------------
// MFMA flash attention, max-free softmax via bare v_exp_f32 (Q pre-scaled by
// log2e). Qs/Ps LDS union (34.8 KB, 4 blocks/CU). XCD-aware 1-D grid.
// ---------------------------------------------------------------------------
__global__ __launch_bounds__(256, 4) void attn_mfma(
    const ush* __restrict__ Qh, const ush* __restrict__ Kh,
    const ush* __restrict__ Vt, ush* __restrict__ ATT)
{
    const int bh = blockIdx.x % BH_;
    const int q0 = (blockIdx.x / BH_) * 128;
    const int tid = threadIdx.x;
    const int w = tid >> 6, lane = tid & 63, l15 = lane & 15, quad = lane >> 4;

    __shared__ __align__(16) ush Ks[64 * 64];
    __shared__ __align__(16) ush Vs[64 * 64];     // [d][slot] swizzled
    __shared__ __align__(16) ush QPs[128 * PS_];  // Qs (16KB) then reused as Ps

    const int sw8 = (l15 & 7);

    {
        const char* qg = (const char*)(Qh + ((size_t)bh * N_ + q0) * DH_);
        #pragma unroll
        for (int i = 0; i < 4; ++i) {
            const int slot = (w * 4 + i) * 64 + lane;
            const int row = slot >> 3, cc = (slot & 7) ^ (row & 7);
            gload_lds16(qg + (size_t)row * 128 + cc * 16, (char*)QPs + slot * 16);
        }
    }
    __syncthreads();

    bf8_t aq[2][2];
    #pragma unroll
    for (int mi = 0; mi < 2; ++mi)
        #pragma unroll
        for (int ks = 0; ks < 2; ++ks)
            aq[mi][ks] = *(const bf8_t*)&QPs[(w * 32 + mi * 16 + l15) * 64 +
                                             (((ks * 4 + quad) ^ sw8) * 8)];

    f4_t O[2][4];
    float l_[2][4];
    #pragma unroll
    for (int mi = 0; mi < 2; ++mi)
        #pragma unroll
        for (int r = 0; r < 4; ++r) {
            l_[mi][r] = 0.f;
            #pragma unroll
            for (int ni = 0; ni < 4; ++ni) O[mi][ni][r] = 0.f;
        }

    const char* kg = (const char*)(Kh + (size_t)bh * N_ * DH_);
    const char* vg = (const char*)(Vt + (size_t)bh * DH_ * N_);

    for (int t = 0; t < 16; ++t) {
        __syncthreads();
        #pragma unroll
        for (int i = 0; i < 2; ++i) {
            const int slot = (w * 2 + i) * 64 + lane;
            const int row = slot >> 3, cc = (slot & 7) ^ (row & 7);
            gload_lds16(kg + (size_t)(t * 64 + row) * 128 + cc * 16,
                        (char*)Ks + slot * 16);
            gload_lds16(vg + (size_t)row * (N_ * 2) + t * 128 + cc * 16,
                        (char*)Vs + slot * 16);
        }
        __syncthreads();

        f4_t s[2][4];
        #pragma unroll
        for (int mi = 0; mi < 2; ++mi)
            #pragma unroll
            for (int ni = 0; ni < 4; ++ni)
                #pragma unroll
                for (int r = 0; r < 4; ++r) s[mi][ni][r] = 0.f;
        #pragma unroll
        for (int ks = 0; ks < 2; ++ks)
            #pragma unroll
            for (int ni = 0; ni < 4; ++ni) {
                bf8_t bk = *(const bf8_t*)&Ks[(ni * 16 + l15) * 64 +
                                              (((ks * 4 + quad) ^ sw8) * 8)];
                #pragma unroll
                for (int mi = 0; mi < 2; ++mi)
                    s[mi][ni] = __builtin_amdgcn_mfma_f32_16x16x32_bf16(
                        aq[mi][ks], bk, s[mi][ni], 0, 0, 0);
            }

        if (t == 15) {
            #pragma unroll
            for (int mi = 0; mi < 2; ++mi)
                #pragma unroll
                for (int r = 0; r < 4; ++r) {
                    const int row = q0 + w * 32 + mi * 16 + quad * 4 + r;
                    if (row < CTX_) { s[mi][2][r] = -1e30f; s[mi][3][r] = -1e30f; }
                }
        }

        // max-free softmax via bare v_exp_f32; packed P (slot s = l15*4 + ni)
        #pragma unroll
        for (int mi = 0; mi < 2; ++mi)
            #pragma unroll
            for (int r = 0; r < 4; ++r) {
                float p0 = fexp2(s[mi][0][r]), p1 = fexp2(s[mi][1][r]);
                float p2 = fexp2(s[mi][2][r]), p3 = fexp2(s[mi][3][r]);
                l_[mi][r] += (p0 + p1) + (p2 + p3);
                ushort4 pk;
                pk.x = f2b(p0); pk.y = f2b(p1); pk.z = f2b(p2); pk.w = f2b(p3);
                *(ushort4*)&QPs[(w * 32 + mi * 16 + quad * 4 + r) * PS_ + l15 * 4] = pk;
            }

        #pragma unroll
        for (int ks = 0; ks < 2; ++ks) {
            bf8_t ap[2];
            #pragma unroll
            for (int mi = 0; mi < 2; ++mi)
                ap[mi] = *(const bf8_t*)&QPs[(w * 32 + mi * 16 + l15) * PS_ +
                                             ks * 32 + quad * 8];
            #pragma unroll
            for (int ni = 0; ni < 4; ++ni) {
                bf8_t bv = *(const bf8_t*)&Vs[(ni * 16 + l15) * 64 +
                                              (((ks * 4 + quad) ^ sw8) * 8)];
                #pragma unroll
                for (int mi = 0; mi < 2; ++mi)
                    O[mi][ni] = __builtin_amdgcn_mfma_f32_16x16x32_bf16(
                        ap[mi], bv, O[mi][ni], 0, 0, 0);
            }
        }
    }

    const int b = bh / H_, h = bh % H_;
    #pragma unroll
    for (int mi = 0; mi < 2; ++mi)
        #pragma unroll
        for (int r = 0; r < 4; ++r) {
            float l = l_[mi][r];
            #pragma unroll
            for (int o = 8; o >= 1; o >>= 1) l += __shfl_xor(l, o);
            const float inv = 1.0f / l;
            const int row = q0 + w * 32 + mi * 16 + quad * 4 + r;
            #pragma unroll
            for (int ni = 0; ni < 4; ++ni)
                ATT[((size_t)b * N_ + row) * DIM_ + h * DH_ + ni * 16 + l15] =
                    f2b(O[mi][ni][r] * inv);
        }
}

// ---------------------------------------------------------------------------
// Merged MFMA GEMM: out = ATT @ Wt^T + bias (fp32 out), single dispatch.
// 128x128 tiles, BK=64 (half the barriers), (256,3): 396 blocks co-resident.
// y<64: ctx rows; y>=64: latent tiles.
// ---------------------------------------------------------------------------
__global__ __launch_bounds__(256, 3) void gemm_o_mfma(
    const ush* __restrict__ ATT, const ush* __restrict__ Btc,
    const float* __restrict__ biasc, const ush* __restrict__ Btl,
    const float* __restrict__ biasl, float* __restrict__ out)
{
    const int lat = (blockIdx.y >= 64);
    const ush* Bt     = lat ? Btl : Btc;
    const float* bias = lat ? biasl : biasc;
    const int m0 = (lat ? (blockIdx.y - 64) : blockIdx.y) * 128;
    const int c0 = blockIdx.x * 128;
    const int tid = threadIdx.x;
    const int w = tid >> 6, lane = tid & 63, l15 = lane & 15, quad = lane >> 4;
    const int wm = w >> 1, wn = w & 1;

    __shared__ __align__(16) ush As[128 * 64];   // 16 KB
    __shared__ __align__(16) ush Bs[128 * 64];   // 16 KB

    const int sw8 = l15 & 7;

    f4_t acc[4][4];
    #pragma unroll
    for (int i = 0; i < 4; ++i)
        #pragma unroll
        for (int j = 0; j < 4; ++j)
            #pragma unroll
            for (int r = 0; r < 4; ++r) acc[i][j][r] = 0.f;

    for (int k0 = 0; k0 < DIM_; k0 += 64) {
        __syncthreads();
        #pragma unroll
        for (int i = 0; i < 4; ++i) {
            const int slot = i * 256 + tid;          // 0..1023
            const int row = slot >> 3, cc = (slot & 7) ^ (row & 7);
            const int am = m0 + row;
            const int grow = lat ? (((am >> 5) << 10) + CTX_ + (am & 31)) : am;
            gload_lds16((const char*)ATT + (size_t)grow * (DIM_ * 2) + k0 * 2 + cc * 16,
                        (char*)As + slot * 16);
            gload_lds16((const char*)Bt + (size_t)(c0 + row) * (DIM_ * 2) + k0 * 2 + cc * 16,
                        (char*)Bs + slot * 16);
        }
        __syncthreads();

        #pragma unroll
        for (int ks = 0; ks < 2; ++ks) {
            bf8_t af[4];
            #pragma unroll
            for (int mi = 0; mi < 4; ++mi)
                af[mi] = *(const bf8_t*)&As[(wm * 64 + mi * 16 + l15) * 64 +
                                            (((ks * 4 + quad) ^ sw8) * 8)];
            #pragma unroll
            for (int ni = 0; ni < 4; ++ni) {
                bf8_t bfr = *(const bf8_t*)&Bs[(wn * 64 + ni * 16 + l15) * 64 +
                                               (((ks * 4 + quad) ^ sw8) * 8)];
                #pragma unroll
                for (int mi = 0; mi < 4; ++mi)
                    acc[mi][ni] = __builtin_amdgcn_mfma_f32_16x16x32_bf16(
                        af[mi], bfr, acc[mi][ni], 0, 0, 0);
            }
        }
    }

    #pragma unroll
    for (int mi = 0; mi < 4; ++mi)
        #pragma unroll
        for (int ni = 0; ni < 4; ++ni) {
            const int c = c0 + wn * 64 + ni * 16 + l15;
            const float bs = bias[c];
            #pragma unroll
            for (int r = 0; r < 4; ++r) {
                const int m = m0 + wm * 64 + mi * 16 + quad * 4 + r;
                if (!lat && (m & 1023) >= CTX_) continue;
                const int grow = lat ? (((m >> 5) << 10) + CTX_ + (m & 31)) : m;
                out[(size_t)grow * DIM_ + c] = acc[mi][ni][r] + bs;
            }
        }
}

// ---------------------------------------------------------------------------
extern "C" void kernel_launch(void* const* d_in, const int* in_sizes, int n_in,
                              void* d_out, int out_size, void* d_ws, size_t ws_size,
                              hipStream_t stream) {
    const float* X      = (const float*)d_in[0];
    const float* Wq     = (const float*)d_in[1];
    const float* Wkv    = (const float*)d_in[2];
    const float* Wo_ctx = (const float*)d_in[3];
    const float* bo_ctx = (const float*)d_in[4];
    const float* Wo_lat = (const float*)d_in[5];
    const float* bo_lat = (const float*)d_in[6];
    const float* ln_g   = (const float*)d_in[7];
    const float* ln_b   = (const float*)d_in[8];
    float* out = (float*)d_out;

    ush* ws = (ush*)d_ws;
    const size_t E = (size_t)BH_ * N_ * DH_;   // 6,291,456
    ush* Xb  = ws;                 // later reused as ATT
    ush* Q16 = ws + E;
    ush* K16 = ws + 2 * E;
    ush* Vt  = ws + 3 * E;
    ush* Wt0 = ws + 4 * E;
    ush* Wt1 = Wt0 + WSZ_;
    ush* Wt2 = Wt1 + WSZ_;
    ush* Wt3 = Wt2 + WSZ_;
    ush* ATT = Xb;                 // alias: Xb dead after gemm_qkv

    cast_all<<<dim3(6144 + 576), 256, 0, stream>>>(X, Xb, Wq, Wkv, Wo_ctx,
                                                   Wo_lat, Wt0, Wt1, Wt2, Wt3);
    gemm_qkv_mfma<<<dim3(6, 64, 2), 256, 0, stream>>>(Xb, Wt0, Wt1, Q16, K16,
                                                      Vt, ln_g, ln_b);
    attn_mfma<<<dim3(8 * BH_), 256, 0, stream>>>(Q16, K16, Vt, ATT);
    gemm_o_mfma<<<dim3(6, 66), 256, 0, stream>>>(ATT, Wt2, bo_ctx, Wt3, bo_lat, out);
}